// Round 5
// baseline (2259.996 us; speedup 1.0000x reference)
//
#include <hip/hip_runtime.h>
#include <math.h>

#define W0F 30.0f
#define NPTS 32768

// f64 sin-path constants: sin(30 z) = sin(2*pi*frac_centered(z * 30/(2*pi)))
#define C_30_OVER_2PI 4.774648292756860070
#define C_2PI         6.283185307179586477

typedef double v4d __attribute__((ext_vector_type(4)));

// ---- workspace layout (float offsets) ----
#define OFF_M     0ull                  // 4 layers * 8 t * 65536
#define SZ_M      2097152ull
#define OFF_CB    (OFF_M + SZ_M)        // 4*8*256
#define SZ_CB     8192ull
#define OFF_AF    (OFF_CB + SZ_CB)      // 4*8*8192
#define SZ_AF     262144ull
#define OFF_BF    (OFF_AF + SZ_AF)
#define SZ_BF     262144ull
#define OFF_HB    (OFF_BF + SZ_BF)      // 4*8*256
#define SZ_HB     8192ull
#define OFF_NSC   (OFF_HB + SZ_HB)      // 4*256 + 1, pad to 2048
#define SZ_NSC    2048ull
#define OFF_BSWZ  (OFF_NSC + SZ_NSC)    // 64 slices x 32768 f32, fragment order
#define SZ_BSWZ   2097152ull
#define OFF_X0    (OFF_BSWZ + SZ_BSWZ)  // ping-pong activation buffers; size
                                        // chosen at launch: T_tile*32768*256
                                        // floats each (T_tile in {8,4,2})
// X0 at OFF_X0, X1 right after (launcher computes).
//
// X SWIZZLED LAYOUT (round-15): element (row, k) of a t-slice lives at
//   slice_base + (row>>4)*4096 + (k>>2)*64 + (k&3)*16 + (row&15)
// so a gemm wave's A-fragment for k-step s (lanes: q=lane>>4, c16=lane&15,
// reading X[w*16+c16][4s+q]) is ONE contiguous 256B segment at
//   base + wave*4096 + 64*s + lane        (vs 16 scattered 64B lines before).
// Producers: layer0_k and gemm_sin (layers 1,2) write swizzled; layer 3
// writes PLAIN layout so final_k is unchanged.

// ---------------------------------------------------------------------------
// S1: per-row L1 scales + all latent-side GEMVs, f64 accumulation, f32 store.
// ---------------------------------------------------------------------------
__global__ __launch_bounds__(256) void setup1(
    const float* __restrict__ latents,
    const float* __restrict__ AwF, const float* __restrict__ AcF,
    const float* __restrict__ AwH, const float* __restrict__ AcH,
    const float* __restrict__ Bw,  const float* __restrict__ Bc,
    const float* __restrict__ hbw, const float* __restrict__ hbc,
    const float* __restrict__ wF,  const float* __restrict__ cF,
    const float* __restrict__ wH,  const float* __restrict__ cH,
    const float* __restrict__ wL,  const float* __restrict__ cL,
    float* __restrict__ AF, float* __restrict__ BFo,
    float* __restrict__ HBo, float* __restrict__ NSC)
{
    __shared__ float lat[1024];
    int tid = threadIdx.x;
    for (int j = tid; j < 1024; j += 256) lat[j] = latents[j];
    __syncthreads();
    int g = blockIdx.x * 256 + tid;
    if (g < 58464) {
        const float* src; float c; float* dst; int stride;
        if (g < 96) {
            src = AwF + g * 128; c = AcF[0]; dst = AF + g; stride = 8192;
        } else if (g < 24672) {
            int q = g - 96; int l = 1 + q / 8192;
            src = AwH + (size_t)q * 128; c = AcH[l - 1];
            dst = AF + (size_t)l * 8 * 8192 + (q % 8192); stride = 8192;
        } else if (g < 57440) {
            int q = g - 24672; int l = q / 8192;
            src = Bw + (size_t)q * 128; c = Bc[l];
            dst = BFo + (size_t)l * 8 * 8192 + (q % 8192); stride = 8192;
        } else {
            int q = g - 57440; int l = q / 256;
            src = hbw + (size_t)q * 128; c = hbc[l];
            dst = HBo + l * 8 * 256 + (q % 256); stride = 256;
        }
        double l1 = 0.0;
        double acc[8] = {0,0,0,0,0,0,0,0};
        for (int kk = 0; kk < 32; ++kk) {
            float4 w4 = ((const float4*)src)[kk];
            l1 += fabs((double)w4.x) + fabs((double)w4.y)
                + fabs((double)w4.z) + fabs((double)w4.w);
            int k = kk * 4;
            #pragma unroll
            for (int t = 0; t < 8; ++t) {
                const float* lp = &lat[t * 128 + k];
                acc[t] = fma((double)w4.x, (double)lp[0], acc[t]);
                acc[t] = fma((double)w4.y, (double)lp[1], acc[t]);
                acc[t] = fma((double)w4.z, (double)lp[2], acc[t]);
                acc[t] = fma((double)w4.w, (double)lp[3], acc[t]);
            }
        }
        double s = fmin(log1p(exp((double)c)) / l1, 1.0);
        #pragma unroll
        for (int t = 0; t < 8; ++t) dst[(size_t)t * stride] = (float)(acc[t] * s);
    } else if (g < 59489) {
        int h = g - 58464;
        if (h < 256) {
            const float* src = wF + h * 3;
            double l1 = fabs((double)src[0]) + fabs((double)src[1]) + fabs((double)src[2]);
            NSC[h] = (float)fmin(log1p(exp((double)cF[0])) / l1, 1.0);
        } else if (h < 1024) {
            int q = h - 256; int l = 1 + q / 256;
            const float* src = wH + (size_t)q * 256;
            double l1 = 0.0;
            for (int kk = 0; kk < 64; ++kk) {
                float4 w4 = ((const float4*)src)[kk];
                l1 += fabs((double)w4.x) + fabs((double)w4.y)
                    + fabs((double)w4.z) + fabs((double)w4.w);
            }
            NSC[256 + q] = (float)fmin(log1p(exp((double)cH[l - 1])) / l1, 1.0);
        } else {
            double l1 = 0.0;
            for (int kk = 0; kk < 64; ++kk) {
                float4 w4 = ((const float4*)wL)[kk];
                l1 += fabs((double)w4.x) + fabs((double)w4.y)
                    + fabs((double)w4.z) + fabs((double)w4.w);
            }
            NSC[1024] = (float)fmin(log1p(exp((double)cL[0])) / l1, 1.0);
        }
    }
}

// ---------------------------------------------------------------------------
// S2: M[l][t][i][o] = W[o,i]*s[o] + sum_r A[i,r]B[r,o]  (f64 acc, f32 store)
// ---------------------------------------------------------------------------
__global__ __launch_bounds__(256) void setup2(
    const float* __restrict__ wF, const float* __restrict__ bF,
    const float* __restrict__ wH, const float* __restrict__ bH,
    const float* __restrict__ AF, const float* __restrict__ BFi,
    const float* __restrict__ HBi, const float* __restrict__ NSC,
    float* __restrict__ Mb, float* __restrict__ CBb)
{
    int b = blockIdx.x; int t = b / 49; int rem = b % 49;
    int o = threadIdx.x;
    int l, i0, ni;
    if (rem == 0) { l = 0; i0 = 0; ni = 3; }
    else { l = 1 + (rem - 1) / 16; i0 = ((rem - 1) % 16) * 16; ni = 16; }
    size_t ltb = (size_t)(l * 8 + t);
    const float* af = AF + ltb * 8192;
    const float* bf = BFi + ltb * 8192;
    double sc = (double)NSC[l * 256 + o];
    float bcol[32];
    #pragma unroll
    for (int r = 0; r < 32; ++r) bcol[r] = bf[r * 256 + o];
    for (int ii = 0; ii < ni; ++ii) {
        int i = i0 + ii;
        float wv = (l == 0) ? wF[o * 3 + i] : wH[(size_t)((l - 1) * 256 + o) * 256 + i];
        double m = (double)wv * sc;
        #pragma unroll
        for (int r = 0; r < 32; ++r)
            m = fma((double)af[i * 32 + r], (double)bcol[r], m);
        Mb[ltb * 65536 + (size_t)i * 256 + o] = (float)m;
    }
    if (rem == 0 || ((rem - 1) % 16) == 0) {
        double bb = (l == 0) ? (double)bF[o] : (double)bH[(l - 1) * 256 + o];
        CBb[ltb * 256 + o] = (float)(bb + (double)HBi[ltb * 256 + o]);
    }
}

// ---------------------------------------------------------------------------
// S3: fragment-ordered **f32** B buffer.
// Layout: slice (ltb,ch); element ((s*2 + h)*64 + lane)*4 + e holds
//   B[k=4s+q][n=(4h+e)*16 + c16] with lane = 16q + c16.
// ---------------------------------------------------------------------------
__global__ __launch_bounds__(256) void setup3(
    const float* __restrict__ Mb, float* __restrict__ Bswz)
{
    int gid = blockIdx.x * 256 + threadIdx.x;   // 0 .. 64*32768-1
    int e    = gid & 3;
    int lane = (gid >> 2) & 63;
    int h    = (gid >> 8) & 1;
    int s    = (gid >> 9) & 63;
    int ltc  = gid >> 15;                       // (ltb, ch)
    int q = lane >> 4, c16 = lane & 15;
    int ltb = ltc >> 1, ch = ltc & 1;
    int n = h * 4 + e;
    Bswz[gid] = Mb[(size_t)ltb * 65536 + (size_t)(4 * s + q) * 256
                   + ch * 128 + n * 16 + c16];
}

// precise activation: sin(30*z) via f64 range reduction + f32 sin on [-pi,pi]
__device__ __forceinline__ float sin30(double z) {
    double u = z * C_30_OVER_2PI;
    double r = u - rint(u);
    return sinf((float)(r * C_2PI));
}

// ---------------------------------------------------------------------------
// L0: x = sin(30*(coords @ M0 + cb)), f64 per element (K=3).
// Writes X in the A-fragment SWIZZLED layout (see header comment).
// ---------------------------------------------------------------------------
__global__ __launch_bounds__(256) void layer0_k(
    const float* __restrict__ coords, const float* __restrict__ Mb,
    const float* __restrict__ CBb, float* __restrict__ X, int tbase)
{
    __shared__ float Ms[3][256];
    __shared__ float cbs[256];
    int tid = threadIdx.x;
    int tl = blockIdx.x >> 10; int rb = blockIdx.x & 1023;
    int t = tbase + tl;
    const float* Mt = Mb + (size_t)t * 65536;
    Ms[0][tid] = Mt[tid]; Ms[1][tid] = Mt[256 + tid]; Ms[2][tid] = Mt[512 + tid];
    cbs[tid] = CBb[t * 256 + tid];
    __syncthreads();
    int r = rb * 32 + (tid >> 3); int lane8 = tid & 7;
    const float* cp = coords + ((size_t)t * NPTS + r) * 3;
    double c0 = (double)cp[0], c1 = (double)cp[1], c2 = (double)cp[2];
    // swizzled destination: slice + (r>>4)*4096 + (r&15); col (k) offsets below
    float* xo = X + (size_t)tl * NPTS * 256 + (size_t)(r >> 4) * 4096 + (r & 15);
#define L0E(col) sin30(fma(c2, (double)Ms[2][col], fma(c1, (double)Ms[1][col], \
                  fma(c0, (double)Ms[0][col], (double)cbs[col]))))
    #pragma unroll
    for (int j = 0; j < 8; ++j) {
        int col = 4 * lane8 + 32 * j;           // divisible by 4: q = 0..3
        int cs  = lane8 + 8 * j;                // col >> 2
        float* p = xo + cs * 64;
        p[0]  = L0E(col + 0);
        p[16] = L0E(col + 1);
        p[32] = L0E(col + 2);
        p[48] = L0E(col + 3);
    }
#undef L0E
}

// ---------------------------------------------------------------------------
// Hidden layer via f64 MFMA, BARRIER-FREE K-loop, Xsrc -> Xdst (ping-pong).
// ROUND-15 CHANGES (theory: exposed HBM latency on 16-segment A-loads):
//  * A reads from the SWIZZLED X layout: one coalesced 256B segment per
//    wave-step (ap[64*s], per-lane offset = lane) instead of 16 x 64B lines.
//  * THREE-deep rotation at #pragma unroll 3 (period == unroll -> compiler
//    renames, zero copies, 3 live sets = round-0 register budget): issue at
//    step s, consume at s+3 -> >= 2 full steps of slack.
//  * D-layout probe AFTER the loop (round-1-verified correct) frees 8 regs
//    during the K-loop.
//  * Epilogue writes swizzled for l<3 (consumed by next gemm), PLAIN for l=3
//    (consumed by final_k).
// Pipe-work floor is 109 us/dispatch (4.19M f64 MFMA @ 64cy/SIMD); rounds
// 0/1/3 all show pipe-busy == ~114 us invariant, so this targets the ~58 us
// of exposed latency, not the pipe.
// ---------------------------------------------------------------------------
__global__ __launch_bounds__(256, 4) void gemm_sin(
    const float* __restrict__ Xsrc, float* __restrict__ Xdst,
    const float* __restrict__ Bswz, const float* __restrict__ CBb,
    int l, int tbase, int swz_out)
{
    int tid = threadIdx.x;
    int b = blockIdx.x;
    int tl = b >> 10;
    int rb = (b >> 1) & 511;
    int ch = b & 1;
    size_t ltb = (size_t)(l * 8 + tbase + tl);
    const float* cbp = CBb + ltb * 256 + ch * 128;
    int wave = tid >> 6, lane = tid & 63;
    int q = lane >> 4, c16 = lane & 15;
    // A fragment pointer (swizzled X): one 256B segment per step
    const float* ap = Xsrc + (size_t)tl * NPTS * 256 + (size_t)rb * 16384
                    + (size_t)wave * 4096 + lane;
    const float* bzl = Bswz + ((size_t)ltb * 2 + ch) * 32768 + lane * 4;
    v4d acc0 = {0.,0.,0.,0.}, acc1 = {0.,0.,0.,0.}, acc2 = {0.,0.,0.,0.},
        acc3 = {0.,0.,0.,0.}, acc4 = {0.,0.,0.,0.}, acc5 = {0.,0.,0.,0.},
        acc6 = {0.,0.,0.,0.}, acc7 = {0.,0.,0.,0.};
    // prologue: 3 sets in flight (steps 0,1,2)
    float  a0 = ap[0];
    float4 b00 = *(const float4*)(bzl + 0 * 256);
    float4 b10 = *(const float4*)(bzl + 1 * 256);
    float  a1 = ap[64];
    float4 b01 = *(const float4*)(bzl + 2 * 256);
    float4 b11 = *(const float4*)(bzl + 3 * 256);
    float  a2 = ap[128];
    float4 b02 = *(const float4*)(bzl + 4 * 256);
    float4 b12 = *(const float4*)(bzl + 5 * 256);
    #pragma unroll 3
    for (int s = 0; s < 64; ++s) {
        double av = (double)a0;
#define TILE(n, bf) { acc##n = __builtin_amdgcn_mfma_f64_16x16x4f64(          \
                               av, (double)(bf), acc##n, 0, 0, 0); }
        TILE(0, b00.x) TILE(1, b00.y) TILE(2, b00.z) TILE(3, b00.w)
        TILE(4, b10.x) TILE(5, b10.y) TILE(6, b10.z) TILE(7, b10.w)
#undef TILE
        int sp = (s < 61) ? s + 3 : 63;          // tail prefetch is redundant
        a0 = a1; a1 = a2; a2 = ap[64 * sp];
        b00 = b01; b10 = b11; b01 = b02; b11 = b12;
        b02 = *(const float4*)(bzl + (size_t)(2 * sp + 0) * 256);
        b12 = *(const float4*)(bzl + (size_t)(2 * sp + 1) * 256);
    }
    // --- D-layout probe (layout-agnostic epilogue indices), post-loop ---
    v4d zz = {0., 0., 0., 0.};
    v4d p1 = __builtin_amdgcn_mfma_f64_16x16x4f64((double)(1 << c16), 1.0, zz, 0, 0, 0);
    v4d p2 = __builtin_amdgcn_mfma_f64_16x16x4f64(1.0, (double)(1 << c16), zz, 0, 0, 0);
    int r0 = 61 - __builtin_clzll((unsigned long long)p1[0]);
    int r1 = 61 - __builtin_clzll((unsigned long long)p1[1]);
    int r2 = 61 - __builtin_clzll((unsigned long long)p1[2]);
    int r3 = 61 - __builtin_clzll((unsigned long long)p1[3]);
    int c0 = 61 - __builtin_clzll((unsigned long long)p2[0]);
    int c1 = 61 - __builtin_clzll((unsigned long long)p2[1]);
    int c2 = 61 - __builtin_clzll((unsigned long long)p2[2]);
    int c3 = 61 - __builtin_clzll((unsigned long long)p2[3]);

    if (swz_out) {
        // swizzled write: elem (row=rb*64+wave*16+rr, gcol=ch*128+n*16+cN) ->
        // slice + (row>>4)*4096 + (gcol>>2)*64 + (gcol&3)*16 + (row&15)
        float* Xw = Xdst + (size_t)tl * NPTS * 256 + (size_t)rb * 16384
                  + (size_t)wave * 4096 + (size_t)ch * 2048;
        int o0 = (c0 >> 2) * 64 + (c0 & 3) * 16 + r0;
        int o1 = (c1 >> 2) * 64 + (c1 & 3) * 16 + r1;
        int o2 = (c2 >> 2) * 64 + (c2 & 3) * 16 + r2;
        int o3 = (c3 >> 2) * 64 + (c3 & 3) * 16 + r3;
#define EPTS(n) {                                                              \
        int cb0 = (n) * 16;                                                    \
        float* Pn = Xw + (n) * 256;                                            \
        Pn[o0] = sin30(acc##n[0] + (double)cbp[cb0 + c0]);                     \
        Pn[o1] = sin30(acc##n[1] + (double)cbp[cb0 + c1]);                     \
        Pn[o2] = sin30(acc##n[2] + (double)cbp[cb0 + c2]);                     \
        Pn[o3] = sin30(acc##n[3] + (double)cbp[cb0 + c3]); }
        EPTS(0) EPTS(1) EPTS(2) EPTS(3)
        EPTS(4) EPTS(5) EPTS(6) EPTS(7)
#undef EPTS
    } else {
        // plain write (layer 3 -> final_k)
        float* Xw = Xdst + ((size_t)tl * NPTS + (size_t)rb * 64) * 256
                  + ch * 128 + (size_t)(wave * 16) * 256;
#define EPT(n) {                                                               \
        int cb0 = (n) * 16;                                                    \
        Xw[r0 * 256 + cb0 + c0] = sin30(acc##n[0] + (double)cbp[cb0 + c0]);    \
        Xw[r1 * 256 + cb0 + c1] = sin30(acc##n[1] + (double)cbp[cb0 + c1]);    \
        Xw[r2 * 256 + cb0 + c2] = sin30(acc##n[2] + (double)cbp[cb0 + c2]);    \
        Xw[r3 * 256 + cb0 + c3] = sin30(acc##n[3] + (double)cbp[cb0 + c3]); }
        EPT(0) EPT(1) EPT(2) EPT(3)
        EPT(4) EPT(5) EPT(6) EPT(7)
#undef EPT
    }
}

// ---------------------------------------------------------------------------
// Final: out[row] = (x_row . w_last)*scale + b_last, f64 dot. One wave per row.
// Reads PLAIN-layout X (layer 3 writes plain).
// ---------------------------------------------------------------------------
__global__ __launch_bounds__(256) void final_k(
    const float* __restrict__ X, const float* __restrict__ wl,
    const float* __restrict__ bl, const float* __restrict__ NSC,
    float* __restrict__ out, int tbase)
{
    int tid = threadIdx.x; int w = tid >> 6; int lane = tid & 63;
    size_t row = (size_t)blockIdx.x * 4 + w;      // local row within T t's
    double ls = (double)NSC[1024];
    float4 wv = ((const float4*)wl)[lane];
    float4 xv = *(const float4*)(X + row * 256 + lane * 4);
    double d = 0.0;
    d = fma((double)wv.x, (double)xv.x, d);
    d = fma((double)wv.y, (double)xv.y, d);
    d = fma((double)wv.z, (double)xv.z, d);
    d = fma((double)wv.w, (double)xv.w, d);
    d *= ls;
    #pragma unroll
    for (int off = 32; off > 0; off >>= 1) d += __shfl_down(d, off, 64);
    if (lane == 0) out[(size_t)tbase * NPTS + row] = (float)(d + (double)bl[0]);
}

extern "C" void kernel_launch(void* const* d_in, const int* in_sizes, int n_in,
                              void* d_out, int out_size, void* d_ws, size_t ws_size,
                              hipStream_t stream)
{
    const float* coords     = (const float*)d_in[0];
    const float* latents    = (const float*)d_in[1];
    const float* nf_w_first = (const float*)d_in[2];
    const float* nf_b_first = (const float*)d_in[3];
    const float* nf_c_first = (const float*)d_in[4];
    const float* nf_w_hid   = (const float*)d_in[5];
    const float* nf_b_hid   = (const float*)d_in[6];
    const float* nf_c_hid   = (const float*)d_in[7];
    const float* nf_w_last  = (const float*)d_in[8];
    const float* nf_b_last  = (const float*)d_in[9];
    const float* nf_c_last  = (const float*)d_in[10];
    const float* Aw_first   = (const float*)d_in[11];
    const float* Ac_first   = (const float*)d_in[12];
    const float* Aw_hid     = (const float*)d_in[13];
    const float* Ac_hid     = (const float*)d_in[14];
    const float* Bw         = (const float*)d_in[15];
    const float* Bc         = (const float*)d_in[16];
    const float* hbw        = (const float*)d_in[17];
    const float* hbc        = (const float*)d_in[18];

    float* ws  = (float*)d_ws;
    float* Mb  = ws + OFF_M;
    float* CBb = ws + OFF_CB;
    float* AF  = ws + OFF_AF;
    float* BFb = ws + OFF_BF;
    float* HBb = ws + OFF_HB;
    float* NSC = ws + OFF_NSC;
    float* Bz  = ws + OFF_BSWZ;
    float* out = (float*)d_out;

    // pick the largest t-tile the workspace can hold: X0+X1 = 2*T*NPTS*256 f32
    size_t availf = ws_size / sizeof(float);
    size_t xslice = (size_t)NPTS * 256;           // floats per t-slice
    int T = 2;
    if (availf >= OFF_X0 + 2ull * 8 * xslice)      T = 8;
    else if (availf >= OFF_X0 + 2ull * 4 * xslice) T = 4;
    float* X0 = ws + OFF_X0;
    float* X1 = X0 + (size_t)T * xslice;

    setup1<<<233, 256, 0, stream>>>(latents, Aw_first, Ac_first, Aw_hid, Ac_hid,
                                    Bw, Bc, hbw, hbc,
                                    nf_w_first, nf_c_first, nf_w_hid, nf_c_hid,
                                    nf_w_last, nf_c_last,
                                    AF, BFb, HBb, NSC);
    setup2<<<392, 256, 0, stream>>>(nf_w_first, nf_b_first, nf_w_hid, nf_b_hid,
                                    AF, BFb, HBb, NSC, Mb, CBb);
    setup3<<<8192, 256, 0, stream>>>(Mb, Bz);
    for (int tbase = 0; tbase < 8; tbase += T) {
        layer0_k<<<1024 * T, 256, 0, stream>>>(coords, Mb, CBb, X0, tbase);
        gemm_sin<<<1024 * T, 256, 0, stream>>>(X0, X1, Bz, CBb, 1, tbase, 1);
        gemm_sin<<<1024 * T, 256, 0, stream>>>(X1, X0, Bz, CBb, 2, tbase, 1);
        gemm_sin<<<1024 * T, 256, 0, stream>>>(X0, X1, Bz, CBb, 3, tbase, 0);
        final_k<<<T * 8192, 256, 0, stream>>>(X1, nf_w_last, nf_b_last, NSC, out, tbase);
    }
}

// Round 7
// 2205.212 us; speedup vs baseline: 1.0248x; 1.0248x over previous
//
#include <hip/hip_runtime.h>
#include <math.h>

#define W0F 30.0f
#define NPTS 32768

// f64 sin-path constants: sin(30 z) = sin(2*pi*frac_centered(z * 30/(2*pi)))
#define C_30_OVER_2PI 4.774648292756860070
#define C_2PI         6.283185307179586477

typedef double v4d __attribute__((ext_vector_type(4)));

// ---- workspace layout (float offsets) ----
#define OFF_M     0ull                  // 4 layers * 8 t * 65536
#define SZ_M      2097152ull
#define OFF_CB    (OFF_M + SZ_M)        // 4*8*256
#define SZ_CB     8192ull
#define OFF_AF    (OFF_CB + SZ_CB)      // 4*8*8192
#define SZ_AF     262144ull
#define OFF_BF    (OFF_AF + SZ_AF)
#define SZ_BF     262144ull
#define OFF_HB    (OFF_BF + SZ_BF)      // 4*8*256
#define SZ_HB     8192ull
#define OFF_NSC   (OFF_HB + SZ_HB)      // 4*256 + 1, pad to 2048
#define SZ_NSC    2048ull
#define OFF_BSWZ  (OFF_NSC + SZ_NSC)    // 64 slices x 32768 f32, fragment order
#define SZ_BSWZ   2097152ull
#define OFF_X0    (OFF_BSWZ + SZ_BSWZ)  // ping-pong activation buffers; size
                                        // chosen at launch: T_tile*32768*256
                                        // floats each (T_tile in {8,4,2})
//
// X SWIZZLED LAYOUT (kept from round-15): element (row, k) of a t-slice at
//   slice_base + (row>>4)*4096 + (k>>2)*64 + (k&3)*16 + (row&15)
// -> a gemm wave's A data for k-step s is ONE contiguous 256B segment at
//   base + wave*4096 + 64*s + lane.
// Producers: layer0_k and gemm_sin (layers 1,2) write swizzled; layer 3
// writes PLAIN layout so final_k is unchanged.

// ---------------------------------------------------------------------------
// S1: per-row L1 scales + all latent-side GEMVs, f64 accumulation, f32 store.
// ---------------------------------------------------------------------------
__global__ __launch_bounds__(256) void setup1(
    const float* __restrict__ latents,
    const float* __restrict__ AwF, const float* __restrict__ AcF,
    const float* __restrict__ AwH, const float* __restrict__ AcH,
    const float* __restrict__ Bw,  const float* __restrict__ Bc,
    const float* __restrict__ hbw, const float* __restrict__ hbc,
    const float* __restrict__ wF,  const float* __restrict__ cF,
    const float* __restrict__ wH,  const float* __restrict__ cH,
    const float* __restrict__ wL,  const float* __restrict__ cL,
    float* __restrict__ AF, float* __restrict__ BFo,
    float* __restrict__ HBo, float* __restrict__ NSC)
{
    __shared__ float lat[1024];
    int tid = threadIdx.x;
    for (int j = tid; j < 1024; j += 256) lat[j] = latents[j];
    __syncthreads();
    int g = blockIdx.x * 256 + tid;
    if (g < 58464) {
        const float* src; float c; float* dst; int stride;
        if (g < 96) {
            src = AwF + g * 128; c = AcF[0]; dst = AF + g; stride = 8192;
        } else if (g < 24672) {
            int q = g - 96; int l = 1 + q / 8192;
            src = AwH + (size_t)q * 128; c = AcH[l - 1];
            dst = AF + (size_t)l * 8 * 8192 + (q % 8192); stride = 8192;
        } else if (g < 57440) {
            int q = g - 24672; int l = q / 8192;
            src = Bw + (size_t)q * 128; c = Bc[l];
            dst = BFo + (size_t)l * 8 * 8192 + (q % 8192); stride = 8192;
        } else {
            int q = g - 57440; int l = q / 256;
            src = hbw + (size_t)q * 128; c = hbc[l];
            dst = HBo + l * 8 * 256 + (q % 256); stride = 256;
        }
        double l1 = 0.0;
        double acc[8] = {0,0,0,0,0,0,0,0};
        for (int kk = 0; kk < 32; ++kk) {
            float4 w4 = ((const float4*)src)[kk];
            l1 += fabs((double)w4.x) + fabs((double)w4.y)
                + fabs((double)w4.z) + fabs((double)w4.w);
            int k = kk * 4;
            #pragma unroll
            for (int t = 0; t < 8; ++t) {
                const float* lp = &lat[t * 128 + k];
                acc[t] = fma((double)w4.x, (double)lp[0], acc[t]);
                acc[t] = fma((double)w4.y, (double)lp[1], acc[t]);
                acc[t] = fma((double)w4.z, (double)lp[2], acc[t]);
                acc[t] = fma((double)w4.w, (double)lp[3], acc[t]);
            }
        }
        double s = fmin(log1p(exp((double)c)) / l1, 1.0);
        #pragma unroll
        for (int t = 0; t < 8; ++t) dst[(size_t)t * stride] = (float)(acc[t] * s);
    } else if (g < 59489) {
        int h = g - 58464;
        if (h < 256) {
            const float* src = wF + h * 3;
            double l1 = fabs((double)src[0]) + fabs((double)src[1]) + fabs((double)src[2]);
            NSC[h] = (float)fmin(log1p(exp((double)cF[0])) / l1, 1.0);
        } else if (h < 1024) {
            int q = h - 256; int l = 1 + q / 256;
            const float* src = wH + (size_t)q * 256;
            double l1 = 0.0;
            for (int kk = 0; kk < 64; ++kk) {
                float4 w4 = ((const float4*)src)[kk];
                l1 += fabs((double)w4.x) + fabs((double)w4.y)
                    + fabs((double)w4.z) + fabs((double)w4.w);
            }
            NSC[256 + q] = (float)fmin(log1p(exp((double)cH[l - 1])) / l1, 1.0);
        } else {
            double l1 = 0.0;
            for (int kk = 0; kk < 64; ++kk) {
                float4 w4 = ((const float4*)wL)[kk];
                l1 += fabs((double)w4.x) + fabs((double)w4.y)
                    + fabs((double)w4.z) + fabs((double)w4.w);
            }
            NSC[1024] = (float)fmin(log1p(exp((double)cL[0])) / l1, 1.0);
        }
    }
}

// ---------------------------------------------------------------------------
// S2: M[l][t][i][o] = W[o,i]*s[o] + sum_r A[i,r]B[r,o]  (f64 acc, f32 store)
// ---------------------------------------------------------------------------
__global__ __launch_bounds__(256) void setup2(
    const float* __restrict__ wF, const float* __restrict__ bF,
    const float* __restrict__ wH, const float* __restrict__ bH,
    const float* __restrict__ AF, const float* __restrict__ BFi,
    const float* __restrict__ HBi, const float* __restrict__ NSC,
    float* __restrict__ Mb, float* __restrict__ CBb)
{
    int b = blockIdx.x; int t = b / 49; int rem = b % 49;
    int o = threadIdx.x;
    int l, i0, ni;
    if (rem == 0) { l = 0; i0 = 0; ni = 3; }
    else { l = 1 + (rem - 1) / 16; i0 = ((rem - 1) % 16) * 16; ni = 16; }
    size_t ltb = (size_t)(l * 8 + t);
    const float* af = AF + ltb * 8192;
    const float* bf = BFi + ltb * 8192;
    double sc = (double)NSC[l * 256 + o];
    float bcol[32];
    #pragma unroll
    for (int r = 0; r < 32; ++r) bcol[r] = bf[r * 256 + o];
    for (int ii = 0; ii < ni; ++ii) {
        int i = i0 + ii;
        float wv = (l == 0) ? wF[o * 3 + i] : wH[(size_t)((l - 1) * 256 + o) * 256 + i];
        double m = (double)wv * sc;
        #pragma unroll
        for (int r = 0; r < 32; ++r)
            m = fma((double)af[i * 32 + r], (double)bcol[r], m);
        Mb[ltb * 65536 + (size_t)i * 256 + o] = (float)m;
    }
    if (rem == 0 || ((rem - 1) % 16) == 0) {
        double bb = (l == 0) ? (double)bF[o] : (double)bH[(l - 1) * 256 + o];
        CBb[ltb * 256 + o] = (float)(bb + (double)HBi[ltb * 256 + o]);
    }
}

// ---------------------------------------------------------------------------
// S3: fragment-ordered **f32** B buffer.
// Layout: slice (ltb,ch); element ((s*2 + h)*64 + lane)*4 + e holds
//   B[k=4s+q][n=(4h+e)*16 + c16] with lane = 16q + c16.
// ---------------------------------------------------------------------------
__global__ __launch_bounds__(256) void setup3(
    const float* __restrict__ Mb, float* __restrict__ Bswz)
{
    int gid = blockIdx.x * 256 + threadIdx.x;   // 0 .. 64*32768-1
    int e    = gid & 3;
    int lane = (gid >> 2) & 63;
    int h    = (gid >> 8) & 1;
    int s    = (gid >> 9) & 63;
    int ltc  = gid >> 15;                       // (ltb, ch)
    int q = lane >> 4, c16 = lane & 15;
    int ltb = ltc >> 1, ch = ltc & 1;
    int n = h * 4 + e;
    Bswz[gid] = Mb[(size_t)ltb * 65536 + (size_t)(4 * s + q) * 256
                   + ch * 128 + n * 16 + c16];
}

// precise activation: sin(30*z) via f64 range reduction + f32 sin on [-pi,pi]
__device__ __forceinline__ float sin30(double z) {
    double u = z * C_30_OVER_2PI;
    double r = u - rint(u);
    return sinf((float)(r * C_2PI));
}

// ---------------------------------------------------------------------------
// L0: x = sin(30*(coords @ M0 + cb)), f64 per element (K=3).
// Writes X in the A-fragment SWIZZLED layout (see header comment).
// ---------------------------------------------------------------------------
__global__ __launch_bounds__(256) void layer0_k(
    const float* __restrict__ coords, const float* __restrict__ Mb,
    const float* __restrict__ CBb, float* __restrict__ X, int tbase)
{
    __shared__ float Ms[3][256];
    __shared__ float cbs[256];
    int tid = threadIdx.x;
    int tl = blockIdx.x >> 10; int rb = blockIdx.x & 1023;
    int t = tbase + tl;
    const float* Mt = Mb + (size_t)t * 65536;
    Ms[0][tid] = Mt[tid]; Ms[1][tid] = Mt[256 + tid]; Ms[2][tid] = Mt[512 + tid];
    cbs[tid] = CBb[t * 256 + tid];
    __syncthreads();
    int r = rb * 32 + (tid >> 3); int lane8 = tid & 7;
    const float* cp = coords + ((size_t)t * NPTS + r) * 3;
    double c0 = (double)cp[0], c1 = (double)cp[1], c2 = (double)cp[2];
    float* xo = X + (size_t)tl * NPTS * 256 + (size_t)(r >> 4) * 4096 + (r & 15);
#define L0E(col) sin30(fma(c2, (double)Ms[2][col], fma(c1, (double)Ms[1][col], \
                  fma(c0, (double)Ms[0][col], (double)cbs[col]))))
    #pragma unroll
    for (int j = 0; j < 8; ++j) {
        int col = 4 * lane8 + 32 * j;           // divisible by 4: q = 0..3
        int cs  = lane8 + 8 * j;                // col >> 2
        float* p = xo + cs * 64;
        p[0]  = L0E(col + 0);
        p[16] = L0E(col + 1);
        p[32] = L0E(col + 2);
        p[48] = L0E(col + 3);
    }
#undef L0E
}

// ---------------------------------------------------------------------------
// Hidden layer via f64 MFMA — ROUND-17: OCCUPANCY DOUBLING (TLP over ILP).
// Ledger: manual pipelines spilled (r1) or raced (r2,r6); setprio null (r3);
// depth-3+swizzle regressed (r5). Diagnosis stands: pipe-busy invariant at
// 112-115us (= analytic floor), ~60us/dispatch exposed latency that compiler
// wait insertion won't let ILP hide. This round attacks it with occupancy:
//  * per-wave tile 16x64 (4 accs = 32 AGPR, was 8/64) -> total regs ~57.
//  * __launch_bounds__(256, 8): under the m69-measured 64-reg cliff ->
//    8 waves/SIMD (was 4). A wave's step-to-step wall gap becomes ~2048cy of
//    other waves' MFMA issue -> 2-deep prefetch covers HBM latency even with
//    conservative per-step waits. No barriers, no asm, no manual vmcnt.
//  * grid 2048/slice (col-QUARTERS c4): A re-read 4x (FETCH ~268MB/dispatch
//    = 43us BW, hidden under the 109us pipe floor).
//  * VERIFIED round-0 rotation loop body; swizzled-X A reads (1 coalesced
//    256B segment/step); post-loop D-probe (r5-verified); plain out for l=3.
// TRIPWIRE: VGPR_Count must be <= 64, WRITE_SIZE flat (~66MB). If VGPR > 64
// the experiment is null (occupancy unchanged) -> revert next round.
// Grid: b = tl<<11 | rb<<2 | c4 ; rb row-tile of 64, c4 col-quarter of 64.
// ---------------------------------------------------------------------------
__global__ __launch_bounds__(256, 8) void gemm_sin(
    const float* __restrict__ Xsrc, float* __restrict__ Xdst,
    const float* __restrict__ Bswz, const float* __restrict__ CBb,
    int l, int tbase, int swz_out)
{
    int tid = threadIdx.x;
    int b = blockIdx.x;
    int tl = b >> 11;
    int rb = (b >> 2) & 511;
    int c4 = b & 3;                       // col-quarter: cols c4*64 .. +63
    size_t ltb = (size_t)(l * 8 + tbase + tl);
    const float* cbp = CBb + ltb * 256 + c4 * 64;
    int wave = tid >> 6, lane = tid & 63;
    int q = lane >> 4, c16 = lane & 15;
    // A: swizzled X, one 256B segment per step
    const float* ap = Xsrc + (size_t)tl * NPTS * 256 + (size_t)rb * 16384
                    + (size_t)wave * 4096 + lane;
    // B: slice ch = c4>>1, subhalf h = c4&1; per step ONE float4 (tiles e=0..3)
    const float* bzl = Bswz + ((size_t)ltb * 2 + (c4 >> 1)) * 32768
                     + (c4 & 1) * 256 + lane * 4;
    v4d acc0 = {0.,0.,0.,0.}, acc1 = {0.,0.,0.,0.},
        acc2 = {0.,0.,0.,0.}, acc3 = {0.,0.,0.,0.};
    // prologue: fragments for s=0 (C) and s=1 (N)
    float  aC = ap[0];
    float4 bC = *(const float4*)(bzl);
    float  aN = ap[64];
    float4 bN = *(const float4*)(bzl + 512);
    #pragma unroll 2
    for (int s = 0; s < 64; ++s) {
        int s2 = (s < 62) ? s + 2 : 63;          // tail prefetch is redundant
        float  aNN = ap[64 * s2];
        float4 bNN = *(const float4*)(bzl + (size_t)s2 * 512);
        double av = (double)aC;
        acc0 = __builtin_amdgcn_mfma_f64_16x16x4f64(av, (double)bC.x, acc0, 0, 0, 0);
        acc1 = __builtin_amdgcn_mfma_f64_16x16x4f64(av, (double)bC.y, acc1, 0, 0, 0);
        acc2 = __builtin_amdgcn_mfma_f64_16x16x4f64(av, (double)bC.z, acc2, 0, 0, 0);
        acc3 = __builtin_amdgcn_mfma_f64_16x16x4f64(av, (double)bC.w, acc3, 0, 0, 0);
        aC = aN; aN = aNN; bC = bN; bN = bNN;
    }
    // --- D-layout probe (layout-agnostic epilogue indices), post-loop ---
    v4d zz = {0., 0., 0., 0.};
    v4d p1 = __builtin_amdgcn_mfma_f64_16x16x4f64((double)(1 << c16), 1.0, zz, 0, 0, 0);
    v4d p2 = __builtin_amdgcn_mfma_f64_16x16x4f64(1.0, (double)(1 << c16), zz, 0, 0, 0);
    int r0 = 61 - __builtin_clzll((unsigned long long)p1[0]);
    int r1 = 61 - __builtin_clzll((unsigned long long)p1[1]);
    int r2 = 61 - __builtin_clzll((unsigned long long)p1[2]);
    int r3 = 61 - __builtin_clzll((unsigned long long)p1[3]);
    int c0 = 61 - __builtin_clzll((unsigned long long)p2[0]);
    int c1 = 61 - __builtin_clzll((unsigned long long)p2[1]);
    int c2 = 61 - __builtin_clzll((unsigned long long)p2[2]);
    int c3 = 61 - __builtin_clzll((unsigned long long)p2[3]);

    if (swz_out) {
        // elem (row=rb*64+wave*16+rr, gcol=c4*64+n*16+cN) ->
        // slice + (row>>4)*4096 + (gcol>>2)*64 + (gcol&3)*16 + (row&15)
        float* Xw = Xdst + (size_t)tl * NPTS * 256 + (size_t)rb * 16384
                  + (size_t)wave * 4096 + (size_t)c4 * 1024;
        int o0 = (c0 >> 2) * 64 + (c0 & 3) * 16 + r0;
        int o1 = (c1 >> 2) * 64 + (c1 & 3) * 16 + r1;
        int o2 = (c2 >> 2) * 64 + (c2 & 3) * 16 + r2;
        int o3 = (c3 >> 2) * 64 + (c3 & 3) * 16 + r3;
#define EPTS(n) {                                                              \
        int cb0 = (n) * 16;                                                    \
        float* Pn = Xw + (n) * 256;                                            \
        Pn[o0] = sin30(acc##n[0] + (double)cbp[cb0 + c0]);                     \
        Pn[o1] = sin30(acc##n[1] + (double)cbp[cb0 + c1]);                     \
        Pn[o2] = sin30(acc##n[2] + (double)cbp[cb0 + c2]);                     \
        Pn[o3] = sin30(acc##n[3] + (double)cbp[cb0 + c3]); }
        EPTS(0) EPTS(1) EPTS(2) EPTS(3)
#undef EPTS
    } else {
        // plain write (layer 3 -> final_k)
        float* Xw = Xdst + ((size_t)tl * NPTS + (size_t)rb * 64
                  + (size_t)(wave * 16)) * 256 + c4 * 64;
#define EPT(n) {                                                               \
        int cb0 = (n) * 16;                                                    \
        Xw[r0 * 256 + cb0 + c0] = sin30(acc##n[0] + (double)cbp[cb0 + c0]);    \
        Xw[r1 * 256 + cb0 + c1] = sin30(acc##n[1] + (double)cbp[cb0 + c1]);    \
        Xw[r2 * 256 + cb0 + c2] = sin30(acc##n[2] + (double)cbp[cb0 + c2]);    \
        Xw[r3 * 256 + cb0 + c3] = sin30(acc##n[3] + (double)cbp[cb0 + c3]); }
        EPT(0) EPT(1) EPT(2) EPT(3)
#undef EPT
    }
}

// ---------------------------------------------------------------------------
// Final: out[row] = (x_row . w_last)*scale + b_last, f64 dot. One wave per row.
// Reads PLAIN-layout X (layer 3 writes plain).
// ---------------------------------------------------------------------------
__global__ __launch_bounds__(256) void final_k(
    const float* __restrict__ X, const float* __restrict__ wl,
    const float* __restrict__ bl, const float* __restrict__ NSC,
    float* __restrict__ out, int tbase)
{
    int tid = threadIdx.x; int w = tid >> 6; int lane = tid & 63;
    size_t row = (size_t)blockIdx.x * 4 + w;      // local row within T t's
    double ls = (double)NSC[1024];
    float4 wv = ((const float4*)wl)[lane];
    float4 xv = *(const float4*)(X + row * 256 + lane * 4);
    double d = 0.0;
    d = fma((double)wv.x, (double)xv.x, d);
    d = fma((double)wv.y, (double)xv.y, d);
    d = fma((double)wv.z, (double)xv.z, d);
    d = fma((double)wv.w, (double)xv.w, d);
    d *= ls;
    #pragma unroll
    for (int off = 32; off > 0; off >>= 1) d += __shfl_down(d, off, 64);
    if (lane == 0) out[(size_t)tbase * NPTS + row] = (float)(d + (double)bl[0]);
}

extern "C" void kernel_launch(void* const* d_in, const int* in_sizes, int n_in,
                              void* d_out, int out_size, void* d_ws, size_t ws_size,
                              hipStream_t stream)
{
    const float* coords     = (const float*)d_in[0];
    const float* latents    = (const float*)d_in[1];
    const float* nf_w_first = (const float*)d_in[2];
    const float* nf_b_first = (const float*)d_in[3];
    const float* nf_c_first = (const float*)d_in[4];
    const float* nf_w_hid   = (const float*)d_in[5];
    const float* nf_b_hid   = (const float*)d_in[6];
    const float* nf_c_hid   = (const float*)d_in[7];
    const float* nf_w_last  = (const float*)d_in[8];
    const float* nf_b_last  = (const float*)d_in[9];
    const float* nf_c_last  = (const float*)d_in[10];
    const float* Aw_first   = (const float*)d_in[11];
    const float* Ac_first   = (const float*)d_in[12];
    const float* Aw_hid     = (const float*)d_in[13];
    const float* Ac_hid     = (const float*)d_in[14];
    const float* Bw         = (const float*)d_in[15];
    const float* Bc         = (const float*)d_in[16];
    const float* hbw        = (const float*)d_in[17];
    const float* hbc        = (const float*)d_in[18];

    float* ws  = (float*)d_ws;
    float* Mb  = ws + OFF_M;
    float* CBb = ws + OFF_CB;
    float* AF  = ws + OFF_AF;
    float* BFb = ws + OFF_BF;
    float* HBb = ws + OFF_HB;
    float* NSC = ws + OFF_NSC;
    float* Bz  = ws + OFF_BSWZ;
    float* out = (float*)d_out;

    // pick the largest t-tile the workspace can hold: X0+X1 = 2*T*NPTS*256 f32
    size_t availf = ws_size / sizeof(float);
    size_t xslice = (size_t)NPTS * 256;           // floats per t-slice
    int T = 2;
    if (availf >= OFF_X0 + 2ull * 8 * xslice)      T = 8;
    else if (availf >= OFF_X0 + 2ull * 4 * xslice) T = 4;
    float* X0 = ws + OFF_X0;
    float* X1 = X0 + (size_t)T * xslice;

    setup1<<<233, 256, 0, stream>>>(latents, Aw_first, Ac_first, Aw_hid, Ac_hid,
                                    Bw, Bc, hbw, hbc,
                                    nf_w_first, nf_c_first, nf_w_hid, nf_c_hid,
                                    nf_w_last, nf_c_last,
                                    AF, BFb, HBb, NSC);
    setup2<<<392, 256, 0, stream>>>(nf_w_first, nf_b_first, nf_w_hid, nf_b_hid,
                                    AF, BFb, HBb, NSC, Mb, CBb);
    setup3<<<8192, 256, 0, stream>>>(Mb, Bz);
    for (int tbase = 0; tbase < 8; tbase += T) {
        layer0_k<<<1024 * T, 256, 0, stream>>>(coords, Mb, CBb, X0, tbase);
        gemm_sin<<<2048 * T, 256, 0, stream>>>(X0, X1, Bz, CBb, 1, tbase, 1);
        gemm_sin<<<2048 * T, 256, 0, stream>>>(X1, X0, Bz, CBb, 2, tbase, 1);
        gemm_sin<<<2048 * T, 256, 0, stream>>>(X0, X1, Bz, CBb, 3, tbase, 0);
        final_k<<<T * 8192, 256, 0, stream>>>(X1, nf_w_last, nf_b_last, NSC, out, tbase);
    }
}

// Round 8
// 2097.797 us; speedup vs baseline: 1.0773x; 1.0512x over previous
//
#include <hip/hip_runtime.h>
#include <math.h>

#define W0F 30.0f
#define NPTS 32768

// f64 sin-path constants: sin(30 z) = sin(2*pi*frac_centered(z * 30/(2*pi)))
#define C_30_OVER_2PI 4.774648292756860070
#define C_2PI         6.283185307179586477

typedef double v4d __attribute__((ext_vector_type(4)));

// ---- workspace layout (float offsets) ----
#define OFF_M     0ull                  // 4 layers * 8 t * 65536
#define SZ_M      2097152ull
#define OFF_CB    (OFF_M + SZ_M)        // 4*8*256
#define SZ_CB     8192ull
#define OFF_AF    (OFF_CB + SZ_CB)      // 4*8*8192
#define SZ_AF     262144ull
#define OFF_BF    (OFF_AF + SZ_AF)
#define SZ_BF     262144ull
#define OFF_HB    (OFF_BF + SZ_BF)      // 4*8*256
#define SZ_HB     8192ull
#define OFF_NSC   (OFF_HB + SZ_HB)      // 4*256 + 1, pad to 2048
#define SZ_NSC    2048ull
#define OFF_BSWZ  (OFF_NSC + SZ_NSC)    // 64 slices x 32768 f32, fragment order
#define SZ_BSWZ   2097152ull
#define OFF_X0    (OFF_BSWZ + SZ_BSWZ)  // SINGLE activation buffer (in-place
                                        // layer updates): T*32768*256 floats,
                                        // T in {8,4,2}
//
// X SWIZZLED LAYOUT (kept): element (row, k) of a t-slice at
//   slice_base + (row>>4)*4096 + (k>>2)*64 + (k&3)*16 + (row&15)
// -> a gemm wave's A data for k-step s is ONE contiguous 256B segment.
// layer0_k and gemm layers 1,2 write swizzled; layer 3 writes PLAIN so
// final_k is unchanged.
//
// ROUND-18 STRUCTURE: gemm blocks are ROW-SELF-CONTAINED (512 thr = 8 waves:
// 4 row-groups x 2 col-halves, 64 rows x 256 cols per block). A block reads
// ONLY its own 64 rows and writes ONLY its own 64 rows -> layer update is
// IN-PLACE (one __syncthreads between last A-read and first store; no
// cross-block data flow). Ping-pong buffer eliminated -> T=4 slices fit the
// existing workspace -> 6 gemm dispatches (was 12), 4 fills each (was 2).
// Rationale: 6 structures all pin pipe-busy at the 109us analytic floor and
// ~63-67% util; r7 falsified latency-exposure (8 waves, util flat). The
// invariant left is dispatch ramp/drain at 2 fills + 12 boundary drains.

// ---------------------------------------------------------------------------
// S1: per-row L1 scales + all latent-side GEMVs, f64 accumulation, f32 store.
// ---------------------------------------------------------------------------
__global__ __launch_bounds__(256) void setup1(
    const float* __restrict__ latents,
    const float* __restrict__ AwF, const float* __restrict__ AcF,
    const float* __restrict__ AwH, const float* __restrict__ AcH,
    const float* __restrict__ Bw,  const float* __restrict__ Bc,
    const float* __restrict__ hbw, const float* __restrict__ hbc,
    const float* __restrict__ wF,  const float* __restrict__ cF,
    const float* __restrict__ wH,  const float* __restrict__ cH,
    const float* __restrict__ wL,  const float* __restrict__ cL,
    float* __restrict__ AF, float* __restrict__ BFo,
    float* __restrict__ HBo, float* __restrict__ NSC)
{
    __shared__ float lat[1024];
    int tid = threadIdx.x;
    for (int j = tid; j < 1024; j += 256) lat[j] = latents[j];
    __syncthreads();
    int g = blockIdx.x * 256 + tid;
    if (g < 58464) {
        const float* src; float c; float* dst; int stride;
        if (g < 96) {
            src = AwF + g * 128; c = AcF[0]; dst = AF + g; stride = 8192;
        } else if (g < 24672) {
            int q = g - 96; int l = 1 + q / 8192;
            src = AwH + (size_t)q * 128; c = AcH[l - 1];
            dst = AF + (size_t)l * 8 * 8192 + (q % 8192); stride = 8192;
        } else if (g < 57440) {
            int q = g - 24672; int l = q / 8192;
            src = Bw + (size_t)q * 128; c = Bc[l];
            dst = BFo + (size_t)l * 8 * 8192 + (q % 8192); stride = 8192;
        } else {
            int q = g - 57440; int l = q / 256;
            src = hbw + (size_t)q * 128; c = hbc[l];
            dst = HBo + l * 8 * 256 + (q % 256); stride = 256;
        }
        double l1 = 0.0;
        double acc[8] = {0,0,0,0,0,0,0,0};
        for (int kk = 0; kk < 32; ++kk) {
            float4 w4 = ((const float4*)src)[kk];
            l1 += fabs((double)w4.x) + fabs((double)w4.y)
                + fabs((double)w4.z) + fabs((double)w4.w);
            int k = kk * 4;
            #pragma unroll
            for (int t = 0; t < 8; ++t) {
                const float* lp = &lat[t * 128 + k];
                acc[t] = fma((double)w4.x, (double)lp[0], acc[t]);
                acc[t] = fma((double)w4.y, (double)lp[1], acc[t]);
                acc[t] = fma((double)w4.z, (double)lp[2], acc[t]);
                acc[t] = fma((double)w4.w, (double)lp[3], acc[t]);
            }
        }
        double s = fmin(log1p(exp((double)c)) / l1, 1.0);
        #pragma unroll
        for (int t = 0; t < 8; ++t) dst[(size_t)t * stride] = (float)(acc[t] * s);
    } else if (g < 59489) {
        int h = g - 58464;
        if (h < 256) {
            const float* src = wF + h * 3;
            double l1 = fabs((double)src[0]) + fabs((double)src[1]) + fabs((double)src[2]);
            NSC[h] = (float)fmin(log1p(exp((double)cF[0])) / l1, 1.0);
        } else if (h < 1024) {
            int q = h - 256; int l = 1 + q / 256;
            const float* src = wH + (size_t)q * 256;
            double l1 = 0.0;
            for (int kk = 0; kk < 64; ++kk) {
                float4 w4 = ((const float4*)src)[kk];
                l1 += fabs((double)w4.x) + fabs((double)w4.y)
                    + fabs((double)w4.z) + fabs((double)w4.w);
            }
            NSC[256 + q] = (float)fmin(log1p(exp((double)cH[l - 1])) / l1, 1.0);
        } else {
            double l1 = 0.0;
            for (int kk = 0; kk < 64; ++kk) {
                float4 w4 = ((const float4*)wL)[kk];
                l1 += fabs((double)w4.x) + fabs((double)w4.y)
                    + fabs((double)w4.z) + fabs((double)w4.w);
            }
            NSC[1024] = (float)fmin(log1p(exp((double)cL[0])) / l1, 1.0);
        }
    }
}

// ---------------------------------------------------------------------------
// S2: M[l][t][i][o] = W[o,i]*s[o] + sum_r A[i,r]B[r,o]  (f64 acc, f32 store)
// ---------------------------------------------------------------------------
__global__ __launch_bounds__(256) void setup2(
    const float* __restrict__ wF, const float* __restrict__ bF,
    const float* __restrict__ wH, const float* __restrict__ bH,
    const float* __restrict__ AF, const float* __restrict__ BFi,
    const float* __restrict__ HBi, const float* __restrict__ NSC,
    float* __restrict__ Mb, float* __restrict__ CBb)
{
    int b = blockIdx.x; int t = b / 49; int rem = b % 49;
    int o = threadIdx.x;
    int l, i0, ni;
    if (rem == 0) { l = 0; i0 = 0; ni = 3; }
    else { l = 1 + (rem - 1) / 16; i0 = ((rem - 1) % 16) * 16; ni = 16; }
    size_t ltb = (size_t)(l * 8 + t);
    const float* af = AF + ltb * 8192;
    const float* bf = BFi + ltb * 8192;
    double sc = (double)NSC[l * 256 + o];
    float bcol[32];
    #pragma unroll
    for (int r = 0; r < 32; ++r) bcol[r] = bf[r * 256 + o];
    for (int ii = 0; ii < ni; ++ii) {
        int i = i0 + ii;
        float wv = (l == 0) ? wF[o * 3 + i] : wH[(size_t)((l - 1) * 256 + o) * 256 + i];
        double m = (double)wv * sc;
        #pragma unroll
        for (int r = 0; r < 32; ++r)
            m = fma((double)af[i * 32 + r], (double)bcol[r], m);
        Mb[ltb * 65536 + (size_t)i * 256 + o] = (float)m;
    }
    if (rem == 0 || ((rem - 1) % 16) == 0) {
        double bb = (l == 0) ? (double)bF[o] : (double)bH[(l - 1) * 256 + o];
        CBb[ltb * 256 + o] = (float)(bb + (double)HBi[ltb * 256 + o]);
    }
}

// ---------------------------------------------------------------------------
// S3: fragment-ordered **f32** B buffer.
// Layout: slice (ltb,ch); element ((s*2 + h)*64 + lane)*4 + e holds
//   B[k=4s+q][n=(4h+e)*16 + c16] with lane = 16q + c16.
// ---------------------------------------------------------------------------
__global__ __launch_bounds__(256) void setup3(
    const float* __restrict__ Mb, float* __restrict__ Bswz)
{
    int gid = blockIdx.x * 256 + threadIdx.x;   // 0 .. 64*32768-1
    int e    = gid & 3;
    int lane = (gid >> 2) & 63;
    int h    = (gid >> 8) & 1;
    int s    = (gid >> 9) & 63;
    int ltc  = gid >> 15;                       // (ltb, ch)
    int q = lane >> 4, c16 = lane & 15;
    int ltb = ltc >> 1, ch = ltc & 1;
    int n = h * 4 + e;
    Bswz[gid] = Mb[(size_t)ltb * 65536 + (size_t)(4 * s + q) * 256
                   + ch * 128 + n * 16 + c16];
}

// precise activation: sin(30*z) via f64 range reduction + f32 sin on [-pi,pi]
__device__ __forceinline__ float sin30(double z) {
    double u = z * C_30_OVER_2PI;
    double r = u - rint(u);
    return sinf((float)(r * C_2PI));
}

// ---------------------------------------------------------------------------
// L0: x = sin(30*(coords @ M0 + cb)), f64 per element (K=3).
// Writes X in the A-fragment SWIZZLED layout.
// ---------------------------------------------------------------------------
__global__ __launch_bounds__(256) void layer0_k(
    const float* __restrict__ coords, const float* __restrict__ Mb,
    const float* __restrict__ CBb, float* __restrict__ X, int tbase)
{
    __shared__ float Ms[3][256];
    __shared__ float cbs[256];
    int tid = threadIdx.x;
    int tl = blockIdx.x >> 10; int rb = blockIdx.x & 1023;
    int t = tbase + tl;
    const float* Mt = Mb + (size_t)t * 65536;
    Ms[0][tid] = Mt[tid]; Ms[1][tid] = Mt[256 + tid]; Ms[2][tid] = Mt[512 + tid];
    cbs[tid] = CBb[t * 256 + tid];
    __syncthreads();
    int r = rb * 32 + (tid >> 3); int lane8 = tid & 7;
    const float* cp = coords + ((size_t)t * NPTS + r) * 3;
    double c0 = (double)cp[0], c1 = (double)cp[1], c2 = (double)cp[2];
    float* xo = X + (size_t)tl * NPTS * 256 + (size_t)(r >> 4) * 4096 + (r & 15);
#define L0E(col) sin30(fma(c2, (double)Ms[2][col], fma(c1, (double)Ms[1][col], \
                  fma(c0, (double)Ms[0][col], (double)cbs[col]))))
    #pragma unroll
    for (int j = 0; j < 8; ++j) {
        int col = 4 * lane8 + 32 * j;           // divisible by 4: q = 0..3
        int cs  = lane8 + 8 * j;                // col >> 2
        float* p = xo + cs * 64;
        p[0]  = L0E(col + 0);
        p[16] = L0E(col + 1);
        p[32] = L0E(col + 2);
        p[48] = L0E(col + 3);
    }
#undef L0E
}

// ---------------------------------------------------------------------------
// Hidden layer via f64 MFMA — ROUND-18: row-self-contained IN-PLACE blocks.
// 512 threads = 8 waves: wave w -> row-group g=w>>1 (16 rows), col-half
// hf=w&1 (128 cols). Block owns rows [rb*64, rb*64+64): reads ONLY them,
// writes ONLY them -> in-place X update (one __syncthreads between K-loop
// and epilogue; blocks are row-disjoint). K-loop body = round-0 VERIFIED
// 2-deep rotation (8 accs); A from swizzled X (1 coalesced 256B seg/step);
// post-loop D-probe (r5-verified); swz_out selects swizzled(l<3)/plain(l=3).
// __launch_bounds__(512,4): 4 waves/SIMD = 2 blocks/CU (128-reg budget,
// same as round-0's regime that measured 56 VGPR no-spill).
// Grid: b = tl<<9 | rb ; 512 blocks/slice, T slices/dispatch -> 4 fills.
// ---------------------------------------------------------------------------
__global__ __launch_bounds__(512, 4) void gemm_sin(
    float* X,                                    // in-place: NOT __restrict__
    const float* __restrict__ Bswz, const float* __restrict__ CBb,
    int l, int tbase, int swz_out)
{
    int tid = threadIdx.x;
    int b = blockIdx.x;
    int tl = b >> 9;
    int rb = b & 511;
    size_t ltb = (size_t)(l * 8 + tbase + tl);
    int wave = tid >> 6, lane = tid & 63;
    int g = wave >> 1, hf = wave & 1;
    int q = lane >> 4, c16 = lane & 15;
    const float* cbp = CBb + ltb * 256 + hf * 128;
    // A: swizzled X, rows rb*64+g*16+c16, one 256B segment per step
    const float* ap = X + (size_t)tl * NPTS * 256
                    + (size_t)(rb * 4 + g) * 4096 + lane;
    // B: fragment-ordered slice (ltb, hf), two float4 per step
    const float* bzl = Bswz + ((size_t)ltb * 2 + hf) * 32768 + lane * 4;
    v4d acc0 = {0.,0.,0.,0.}, acc1 = {0.,0.,0.,0.}, acc2 = {0.,0.,0.,0.},
        acc3 = {0.,0.,0.,0.}, acc4 = {0.,0.,0.,0.}, acc5 = {0.,0.,0.,0.},
        acc6 = {0.,0.,0.,0.}, acc7 = {0.,0.,0.,0.};
    // prologue: fragments for s=0 (C) and s=1 (N)
    float  aC  = ap[0];
    float4 bC0 = *(const float4*)(bzl + 0 * 256);
    float4 bC1 = *(const float4*)(bzl + 1 * 256);
    float  aN  = ap[64];
    float4 bN0 = *(const float4*)(bzl + 2 * 256);
    float4 bN1 = *(const float4*)(bzl + 3 * 256);
    #pragma unroll 2
    for (int s = 0; s < 64; ++s) {
        int s2 = (s < 62) ? s + 2 : 63;          // tail prefetch is redundant
        float  aNN  = ap[64 * s2];
        float4 bNN0 = *(const float4*)(bzl + (size_t)(s2 * 2 + 0) * 256);
        float4 bNN1 = *(const float4*)(bzl + (size_t)(s2 * 2 + 1) * 256);
        double av = (double)aC;
#define TILE(n, bf) { acc##n = __builtin_amdgcn_mfma_f64_16x16x4f64(          \
                               av, (double)(bf), acc##n, 0, 0, 0); }
        TILE(0, bC0.x) TILE(1, bC0.y) TILE(2, bC0.z) TILE(3, bC0.w)
        TILE(4, bC1.x) TILE(5, bC1.y) TILE(6, bC1.z) TILE(7, bC1.w)
#undef TILE
        aC = aN;  aN = aNN;
        bC0 = bN0; bC1 = bN1; bN0 = bNN0; bN1 = bNN1;
    }
    // in-place safety: ALL waves of this block finished reading rows
    // [rb*64, rb*64+64) before any store to them.
    __syncthreads();

    // --- D-layout probe (layout-agnostic epilogue indices), post-loop ---
    v4d zz = {0., 0., 0., 0.};
    v4d p1 = __builtin_amdgcn_mfma_f64_16x16x4f64((double)(1 << c16), 1.0, zz, 0, 0, 0);
    v4d p2 = __builtin_amdgcn_mfma_f64_16x16x4f64(1.0, (double)(1 << c16), zz, 0, 0, 0);
    int r0 = 61 - __builtin_clzll((unsigned long long)p1[0]);
    int r1 = 61 - __builtin_clzll((unsigned long long)p1[1]);
    int r2 = 61 - __builtin_clzll((unsigned long long)p1[2]);
    int r3 = 61 - __builtin_clzll((unsigned long long)p1[3]);
    int c0 = 61 - __builtin_clzll((unsigned long long)p2[0]);
    int c1 = 61 - __builtin_clzll((unsigned long long)p2[1]);
    int c2 = 61 - __builtin_clzll((unsigned long long)p2[2]);
    int c3 = 61 - __builtin_clzll((unsigned long long)p2[3]);

    if (swz_out) {
        // swizzled in-place write: gcol = hf*128 + n*16 + cN ->
        // region base + hf*2048 + n*256 + (c>>2)*64 + (c&3)*16 + r
        float* Xw = X + (size_t)tl * NPTS * 256
                  + (size_t)(rb * 4 + g) * 4096 + (size_t)hf * 2048;
        int o0 = (c0 >> 2) * 64 + (c0 & 3) * 16 + r0;
        int o1 = (c1 >> 2) * 64 + (c1 & 3) * 16 + r1;
        int o2 = (c2 >> 2) * 64 + (c2 & 3) * 16 + r2;
        int o3 = (c3 >> 2) * 64 + (c3 & 3) * 16 + r3;
#define EPTS(n) {                                                              \
        int cb0 = (n) * 16;                                                    \
        float* Pn = Xw + (n) * 256;                                            \
        Pn[o0] = sin30(acc##n[0] + (double)cbp[cb0 + c0]);                     \
        Pn[o1] = sin30(acc##n[1] + (double)cbp[cb0 + c1]);                     \
        Pn[o2] = sin30(acc##n[2] + (double)cbp[cb0 + c2]);                     \
        Pn[o3] = sin30(acc##n[3] + (double)cbp[cb0 + c3]); }
        EPTS(0) EPTS(1) EPTS(2) EPTS(3)
        EPTS(4) EPTS(5) EPTS(6) EPTS(7)
#undef EPTS
    } else {
        // plain in-place write (layer 3 -> final_k)
        float* Xw = X + ((size_t)tl * NPTS + (size_t)(rb * 64 + g * 16)) * 256
                  + hf * 128;
#define EPT(n) {                                                               \
        int cb0 = (n) * 16;                                                    \
        Xw[r0 * 256 + cb0 + c0] = sin30(acc##n[0] + (double)cbp[cb0 + c0]);    \
        Xw[r1 * 256 + cb0 + c1] = sin30(acc##n[1] + (double)cbp[cb0 + c1]);    \
        Xw[r2 * 256 + cb0 + c2] = sin30(acc##n[2] + (double)cbp[cb0 + c2]);    \
        Xw[r3 * 256 + cb0 + c3] = sin30(acc##n[3] + (double)cbp[cb0 + c3]); }
        EPT(0) EPT(1) EPT(2) EPT(3)
        EPT(4) EPT(5) EPT(6) EPT(7)
#undef EPT
    }
}

// ---------------------------------------------------------------------------
// Final: out[row] = (x_row . w_last)*scale + b_last, f64 dot. One wave per row.
// Reads PLAIN-layout X (layer 3 writes plain).
// ---------------------------------------------------------------------------
__global__ __launch_bounds__(256) void final_k(
    const float* __restrict__ X, const float* __restrict__ wl,
    const float* __restrict__ bl, const float* __restrict__ NSC,
    float* __restrict__ out, int tbase)
{
    int tid = threadIdx.x; int w = tid >> 6; int lane = tid & 63;
    size_t row = (size_t)blockIdx.x * 4 + w;      // local row within T t's
    double ls = (double)NSC[1024];
    float4 wv = ((const float4*)wl)[lane];
    float4 xv = *(const float4*)(X + row * 256 + lane * 4);
    double d = 0.0;
    d = fma((double)wv.x, (double)xv.x, d);
    d = fma((double)wv.y, (double)xv.y, d);
    d = fma((double)wv.z, (double)xv.z, d);
    d = fma((double)wv.w, (double)xv.w, d);
    d *= ls;
    #pragma unroll
    for (int off = 32; off > 0; off >>= 1) d += __shfl_down(d, off, 64);
    if (lane == 0) out[(size_t)tbase * NPTS + row] = (float)(d + (double)bl[0]);
}

extern "C" void kernel_launch(void* const* d_in, const int* in_sizes, int n_in,
                              void* d_out, int out_size, void* d_ws, size_t ws_size,
                              hipStream_t stream)
{
    const float* coords     = (const float*)d_in[0];
    const float* latents    = (const float*)d_in[1];
    const float* nf_w_first = (const float*)d_in[2];
    const float* nf_b_first = (const float*)d_in[3];
    const float* nf_c_first = (const float*)d_in[4];
    const float* nf_w_hid   = (const float*)d_in[5];
    const float* nf_b_hid   = (const float*)d_in[6];
    const float* nf_c_hid   = (const float*)d_in[7];
    const float* nf_w_last  = (const float*)d_in[8];
    const float* nf_b_last  = (const float*)d_in[9];
    const float* nf_c_last  = (const float*)d_in[10];
    const float* Aw_first   = (const float*)d_in[11];
    const float* Ac_first   = (const float*)d_in[12];
    const float* Aw_hid     = (const float*)d_in[13];
    const float* Ac_hid     = (const float*)d_in[14];
    const float* Bw         = (const float*)d_in[15];
    const float* Bc         = (const float*)d_in[16];
    const float* hbw        = (const float*)d_in[17];
    const float* hbc        = (const float*)d_in[18];

    float* ws  = (float*)d_ws;
    float* Mb  = ws + OFF_M;
    float* CBb = ws + OFF_CB;
    float* AF  = ws + OFF_AF;
    float* BFb = ws + OFF_BF;
    float* HBb = ws + OFF_HB;
    float* NSC = ws + OFF_NSC;
    float* Bz  = ws + OFF_BSWZ;
    float* out = (float*)d_out;

    // single X buffer (in-place layers): pick largest T that fits
    size_t availf = ws_size / sizeof(float);
    size_t xslice = (size_t)NPTS * 256;           // floats per t-slice
    int T = 2;
    if (availf >= OFF_X0 + 8ull * xslice)      T = 8;
    else if (availf >= OFF_X0 + 4ull * xslice) T = 4;
    float* X0 = ws + OFF_X0;

    setup1<<<233, 256, 0, stream>>>(latents, Aw_first, Ac_first, Aw_hid, Ac_hid,
                                    Bw, Bc, hbw, hbc,
                                    nf_w_first, nf_c_first, nf_w_hid, nf_c_hid,
                                    nf_w_last, nf_c_last,
                                    AF, BFb, HBb, NSC);
    setup2<<<392, 256, 0, stream>>>(nf_w_first, nf_b_first, nf_w_hid, nf_b_hid,
                                    AF, BFb, HBb, NSC, Mb, CBb);
    setup3<<<8192, 256, 0, stream>>>(Mb, Bz);
    for (int tbase = 0; tbase < 8; tbase += T) {
        layer0_k<<<1024 * T, 256, 0, stream>>>(coords, Mb, CBb, X0, tbase);
        gemm_sin<<<512 * T, 512, 0, stream>>>(X0, Bz, CBb, 1, tbase, 1);
        gemm_sin<<<512 * T, 512, 0, stream>>>(X0, Bz, CBb, 2, tbase, 1);
        gemm_sin<<<512 * T, 512, 0, stream>>>(X0, Bz, CBb, 3, tbase, 0);
        final_k<<<T * 8192, 256, 0, stream>>>(X0, nf_w_last, nf_b_last, NSC, out, tbase);
    }
}

// Round 9
// 2049.025 us; speedup vs baseline: 1.1030x; 1.0238x over previous
//
#include <hip/hip_runtime.h>
#include <math.h>

#define W0F 30.0f
#define NPTS 32768

// f64 sin-path constants: sin(30 z) = sin(2*pi*frac_centered(z * 30/(2*pi)))
#define C_30_OVER_2PI 4.774648292756860070
#define C_2PI         6.283185307179586477

typedef double v4d __attribute__((ext_vector_type(4)));

// ---- workspace layout (float offsets) ----
#define OFF_M     0ull                  // 4 layers * 8 t * 65536
#define SZ_M      2097152ull
#define OFF_CB    (OFF_M + SZ_M)        // 4*8*256
#define SZ_CB     8192ull
#define OFF_AF    (OFF_CB + SZ_CB)      // 4*8*8192
#define SZ_AF     262144ull
#define OFF_BF    (OFF_AF + SZ_AF)
#define SZ_BF     262144ull
#define OFF_HB    (OFF_BF + SZ_BF)      // 4*8*256
#define SZ_HB     8192ull
#define OFF_NSC   (OFF_HB + SZ_HB)      // 4*256 + 1, pad to 2048
#define SZ_NSC    2048ull
#define OFF_BSWZ  (OFF_NSC + SZ_NSC)    // 64 slices x 32768 f32, fragment order
#define SZ_BSWZ   2097152ull
#define OFF_X0    (OFF_BSWZ + SZ_BSWZ)  // SINGLE activation buffer (in-place
                                        // layer updates): T*32768*256 floats,
                                        // T in {8,4,2}
//
// X SWIZZLED LAYOUT (kept): element (row, k) of a t-slice at
//   slice_base + (row>>4)*4096 + (k>>2)*64 + (k&3)*16 + (row&15)
// -> a gemm wave's A data for k-step s is ONE contiguous 256B segment.
// layer0_k and gemm layers 1,2 write swizzled; layer 3 writes PLAIN so
// final_k is unchanged.
//
// ROUND-19: round-8 structure (row-self-contained in-place blocks, T=4,
// 6 gemm dispatches) + T19 sched_group_barrier emission pinning in the
// K-loop. 8 structures have pinned pipe-busy at the analytic f64-MFMA floor
// with ~33% exposure invariant under prefetch depth, occupancy, LDS, fills —
// every RESOURCE theory is dead. Last untested lever: EMISSION ORDER. If the
// step is emitted [VALU+VMEM blob][MFMA blob], convoyed waves idle the
// matrix pipe for the blob window each step, independent of all the above.
// SGB pins 3 VMEM issues under the first MFMAs (compile-time only: cannot
// race / spill / change waits). Null => declare structural ceiling.

// ---------------------------------------------------------------------------
// S1: per-row L1 scales + all latent-side GEMVs, f64 accumulation, f32 store.
// ---------------------------------------------------------------------------
__global__ __launch_bounds__(256) void setup1(
    const float* __restrict__ latents,
    const float* __restrict__ AwF, const float* __restrict__ AcF,
    const float* __restrict__ AwH, const float* __restrict__ AcH,
    const float* __restrict__ Bw,  const float* __restrict__ Bc,
    const float* __restrict__ hbw, const float* __restrict__ hbc,
    const float* __restrict__ wF,  const float* __restrict__ cF,
    const float* __restrict__ wH,  const float* __restrict__ cH,
    const float* __restrict__ wL,  const float* __restrict__ cL,
    float* __restrict__ AF, float* __restrict__ BFo,
    float* __restrict__ HBo, float* __restrict__ NSC)
{
    __shared__ float lat[1024];
    int tid = threadIdx.x;
    for (int j = tid; j < 1024; j += 256) lat[j] = latents[j];
    __syncthreads();
    int g = blockIdx.x * 256 + tid;
    if (g < 58464) {
        const float* src; float c; float* dst; int stride;
        if (g < 96) {
            src = AwF + g * 128; c = AcF[0]; dst = AF + g; stride = 8192;
        } else if (g < 24672) {
            int q = g - 96; int l = 1 + q / 8192;
            src = AwH + (size_t)q * 128; c = AcH[l - 1];
            dst = AF + (size_t)l * 8 * 8192 + (q % 8192); stride = 8192;
        } else if (g < 57440) {
            int q = g - 24672; int l = q / 8192;
            src = Bw + (size_t)q * 128; c = Bc[l];
            dst = BFo + (size_t)l * 8 * 8192 + (q % 8192); stride = 8192;
        } else {
            int q = g - 57440; int l = q / 256;
            src = hbw + (size_t)q * 128; c = hbc[l];
            dst = HBo + l * 8 * 256 + (q % 256); stride = 256;
        }
        double l1 = 0.0;
        double acc[8] = {0,0,0,0,0,0,0,0};
        for (int kk = 0; kk < 32; ++kk) {
            float4 w4 = ((const float4*)src)[kk];
            l1 += fabs((double)w4.x) + fabs((double)w4.y)
                + fabs((double)w4.z) + fabs((double)w4.w);
            int k = kk * 4;
            #pragma unroll
            for (int t = 0; t < 8; ++t) {
                const float* lp = &lat[t * 128 + k];
                acc[t] = fma((double)w4.x, (double)lp[0], acc[t]);
                acc[t] = fma((double)w4.y, (double)lp[1], acc[t]);
                acc[t] = fma((double)w4.z, (double)lp[2], acc[t]);
                acc[t] = fma((double)w4.w, (double)lp[3], acc[t]);
            }
        }
        double s = fmin(log1p(exp((double)c)) / l1, 1.0);
        #pragma unroll
        for (int t = 0; t < 8; ++t) dst[(size_t)t * stride] = (float)(acc[t] * s);
    } else if (g < 59489) {
        int h = g - 58464;
        if (h < 256) {
            const float* src = wF + h * 3;
            double l1 = fabs((double)src[0]) + fabs((double)src[1]) + fabs((double)src[2]);
            NSC[h] = (float)fmin(log1p(exp((double)cF[0])) / l1, 1.0);
        } else if (h < 1024) {
            int q = h - 256; int l = 1 + q / 256;
            const float* src = wH + (size_t)q * 256;
            double l1 = 0.0;
            for (int kk = 0; kk < 64; ++kk) {
                float4 w4 = ((const float4*)src)[kk];
                l1 += fabs((double)w4.x) + fabs((double)w4.y)
                    + fabs((double)w4.z) + fabs((double)w4.w);
            }
            NSC[256 + q] = (float)fmin(log1p(exp((double)cH[l - 1])) / l1, 1.0);
        } else {
            double l1 = 0.0;
            for (int kk = 0; kk < 64; ++kk) {
                float4 w4 = ((const float4*)wL)[kk];
                l1 += fabs((double)w4.x) + fabs((double)w4.y)
                    + fabs((double)w4.z) + fabs((double)w4.w);
            }
            NSC[1024] = (float)fmin(log1p(exp((double)cL[0])) / l1, 1.0);
        }
    }
}

// ---------------------------------------------------------------------------
// S2: M[l][t][i][o] = W[o,i]*s[o] + sum_r A[i,r]B[r,o]  (f64 acc, f32 store)
// ---------------------------------------------------------------------------
__global__ __launch_bounds__(256) void setup2(
    const float* __restrict__ wF, const float* __restrict__ bF,
    const float* __restrict__ wH, const float* __restrict__ bH,
    const float* __restrict__ AF, const float* __restrict__ BFi,
    const float* __restrict__ HBi, const float* __restrict__ NSC,
    float* __restrict__ Mb, float* __restrict__ CBb)
{
    int b = blockIdx.x; int t = b / 49; int rem = b % 49;
    int o = threadIdx.x;
    int l, i0, ni;
    if (rem == 0) { l = 0; i0 = 0; ni = 3; }
    else { l = 1 + (rem - 1) / 16; i0 = ((rem - 1) % 16) * 16; ni = 16; }
    size_t ltb = (size_t)(l * 8 + t);
    const float* af = AF + ltb * 8192;
    const float* bf = BFi + ltb * 8192;
    double sc = (double)NSC[l * 256 + o];
    float bcol[32];
    #pragma unroll
    for (int r = 0; r < 32; ++r) bcol[r] = bf[r * 256 + o];
    for (int ii = 0; ii < ni; ++ii) {
        int i = i0 + ii;
        float wv = (l == 0) ? wF[o * 3 + i] : wH[(size_t)((l - 1) * 256 + o) * 256 + i];
        double m = (double)wv * sc;
        #pragma unroll
        for (int r = 0; r < 32; ++r)
            m = fma((double)af[i * 32 + r], (double)bcol[r], m);
        Mb[ltb * 65536 + (size_t)i * 256 + o] = (float)m;
    }
    if (rem == 0 || ((rem - 1) % 16) == 0) {
        double bb = (l == 0) ? (double)bF[o] : (double)bH[(l - 1) * 256 + o];
        CBb[ltb * 256 + o] = (float)(bb + (double)HBi[ltb * 256 + o]);
    }
}

// ---------------------------------------------------------------------------
// S3: fragment-ordered **f32** B buffer.
// Layout: slice (ltb,ch); element ((s*2 + h)*64 + lane)*4 + e holds
//   B[k=4s+q][n=(4h+e)*16 + c16] with lane = 16q + c16.
// ---------------------------------------------------------------------------
__global__ __launch_bounds__(256) void setup3(
    const float* __restrict__ Mb, float* __restrict__ Bswz)
{
    int gid = blockIdx.x * 256 + threadIdx.x;   // 0 .. 64*32768-1
    int e    = gid & 3;
    int lane = (gid >> 2) & 63;
    int h    = (gid >> 8) & 1;
    int s    = (gid >> 9) & 63;
    int ltc  = gid >> 15;                       // (ltb, ch)
    int q = lane >> 4, c16 = lane & 15;
    int ltb = ltc >> 1, ch = ltc & 1;
    int n = h * 4 + e;
    Bswz[gid] = Mb[(size_t)ltb * 65536 + (size_t)(4 * s + q) * 256
                   + ch * 128 + n * 16 + c16];
}

// precise activation: sin(30*z) via f64 range reduction + f32 sin on [-pi,pi]
__device__ __forceinline__ float sin30(double z) {
    double u = z * C_30_OVER_2PI;
    double r = u - rint(u);
    return sinf((float)(r * C_2PI));
}

// ---------------------------------------------------------------------------
// L0: x = sin(30*(coords @ M0 + cb)), f64 per element (K=3).
// Writes X in the A-fragment SWIZZLED layout.
// ---------------------------------------------------------------------------
__global__ __launch_bounds__(256) void layer0_k(
    const float* __restrict__ coords, const float* __restrict__ Mb,
    const float* __restrict__ CBb, float* __restrict__ X, int tbase)
{
    __shared__ float Ms[3][256];
    __shared__ float cbs[256];
    int tid = threadIdx.x;
    int tl = blockIdx.x >> 10; int rb = blockIdx.x & 1023;
    int t = tbase + tl;
    const float* Mt = Mb + (size_t)t * 65536;
    Ms[0][tid] = Mt[tid]; Ms[1][tid] = Mt[256 + tid]; Ms[2][tid] = Mt[512 + tid];
    cbs[tid] = CBb[t * 256 + tid];
    __syncthreads();
    int r = rb * 32 + (tid >> 3); int lane8 = tid & 7;
    const float* cp = coords + ((size_t)t * NPTS + r) * 3;
    double c0 = (double)cp[0], c1 = (double)cp[1], c2 = (double)cp[2];
    float* xo = X + (size_t)tl * NPTS * 256 + (size_t)(r >> 4) * 4096 + (r & 15);
#define L0E(col) sin30(fma(c2, (double)Ms[2][col], fma(c1, (double)Ms[1][col], \
                  fma(c0, (double)Ms[0][col], (double)cbs[col]))))
    #pragma unroll
    for (int j = 0; j < 8; ++j) {
        int col = 4 * lane8 + 32 * j;           // divisible by 4: q = 0..3
        int cs  = lane8 + 8 * j;                // col >> 2
        float* p = xo + cs * 64;
        p[0]  = L0E(col + 0);
        p[16] = L0E(col + 1);
        p[32] = L0E(col + 2);
        p[48] = L0E(col + 3);
    }
#undef L0E
}

// ---------------------------------------------------------------------------
// Hidden layer via f64 MFMA — ROUND-19: r8 structure + sched_group_barrier
// emission pinning (T19): per K-step, 3 VMEM issues are interleaved under the
// first MFMAs of the cluster so the step's serial non-MFMA window shrinks.
// Compile-time directive only — no registers, no barriers, no wait changes.
// 512 threads = 8 waves: wave w -> row-group g=w>>1 (16 rows), col-half
// hf=w&1 (128 cols). Block owns rows [rb*64, +64): in-place X update.
// ---------------------------------------------------------------------------
__global__ __launch_bounds__(512, 4) void gemm_sin(
    float* X,                                    // in-place: NOT __restrict__
    const float* __restrict__ Bswz, const float* __restrict__ CBb,
    int l, int tbase, int swz_out)
{
    int tid = threadIdx.x;
    int b = blockIdx.x;
    int tl = b >> 9;
    int rb = b & 511;
    size_t ltb = (size_t)(l * 8 + tbase + tl);
    int wave = tid >> 6, lane = tid & 63;
    int g = wave >> 1, hf = wave & 1;
    int q = lane >> 4, c16 = lane & 15;
    const float* cbp = CBb + ltb * 256 + hf * 128;
    // A: swizzled X, rows rb*64+g*16+c16, one 256B segment per step
    const float* ap = X + (size_t)tl * NPTS * 256
                    + (size_t)(rb * 4 + g) * 4096 + lane;
    // B: fragment-ordered slice (ltb, hf), two float4 per step
    const float* bzl = Bswz + ((size_t)ltb * 2 + hf) * 32768 + lane * 4;
    v4d acc0 = {0.,0.,0.,0.}, acc1 = {0.,0.,0.,0.}, acc2 = {0.,0.,0.,0.},
        acc3 = {0.,0.,0.,0.}, acc4 = {0.,0.,0.,0.}, acc5 = {0.,0.,0.,0.},
        acc6 = {0.,0.,0.,0.}, acc7 = {0.,0.,0.,0.};
    // prologue: fragments for s=0 (C) and s=1 (N)
    float  aC  = ap[0];
    float4 bC0 = *(const float4*)(bzl + 0 * 256);
    float4 bC1 = *(const float4*)(bzl + 1 * 256);
    float  aN  = ap[64];
    float4 bN0 = *(const float4*)(bzl + 2 * 256);
    float4 bN1 = *(const float4*)(bzl + 3 * 256);
    #pragma unroll 2
    for (int s = 0; s < 64; ++s) {
        int s2 = (s < 62) ? s + 2 : 63;          // tail prefetch is redundant
        float  aNN  = ap[64 * s2];
        float4 bNN0 = *(const float4*)(bzl + (size_t)(s2 * 2 + 0) * 256);
        float4 bNN1 = *(const float4*)(bzl + (size_t)(s2 * 2 + 1) * 256);
        double av = (double)aC;
#define TILE(n, bf) { acc##n = __builtin_amdgcn_mfma_f64_16x16x4f64(          \
                               av, (double)(bf), acc##n, 0, 0, 0); }
        TILE(0, bC0.x) TILE(1, bC0.y) TILE(2, bC0.z) TILE(3, bC0.w)
        TILE(4, bC1.x) TILE(5, bC1.y) TILE(6, bC1.z) TILE(7, bC1.w)
#undef TILE
        aC = aN;  aN = aNN;
        bC0 = bN0; bC1 = bN1; bN0 = bNN0; bN1 = bNN1;
        // T19 emission pinning: first MFMA, then the 3 prefetch VMEM issues
        // spread under the MFMA cluster, then the rest. VALU left free.
        __builtin_amdgcn_sched_group_barrier(0x008, 1, 0);  // MFMA x1
        __builtin_amdgcn_sched_group_barrier(0x020, 1, 0);  // VMEM_READ x1
        __builtin_amdgcn_sched_group_barrier(0x008, 1, 0);  // MFMA x1
        __builtin_amdgcn_sched_group_barrier(0x020, 1, 0);  // VMEM_READ x1
        __builtin_amdgcn_sched_group_barrier(0x008, 1, 0);  // MFMA x1
        __builtin_amdgcn_sched_group_barrier(0x020, 1, 0);  // VMEM_READ x1
        __builtin_amdgcn_sched_group_barrier(0x008, 5, 0);  // MFMA x5
    }
    // in-place safety: ALL waves of this block finished reading rows
    // [rb*64, rb*64+64) before any store to them.
    __syncthreads();

    // --- D-layout probe (layout-agnostic epilogue indices), post-loop ---
    v4d zz = {0., 0., 0., 0.};
    v4d p1 = __builtin_amdgcn_mfma_f64_16x16x4f64((double)(1 << c16), 1.0, zz, 0, 0, 0);
    v4d p2 = __builtin_amdgcn_mfma_f64_16x16x4f64(1.0, (double)(1 << c16), zz, 0, 0, 0);
    int r0 = 61 - __builtin_clzll((unsigned long long)p1[0]);
    int r1 = 61 - __builtin_clzll((unsigned long long)p1[1]);
    int r2 = 61 - __builtin_clzll((unsigned long long)p1[2]);
    int r3 = 61 - __builtin_clzll((unsigned long long)p1[3]);
    int c0 = 61 - __builtin_clzll((unsigned long long)p2[0]);
    int c1 = 61 - __builtin_clzll((unsigned long long)p2[1]);
    int c2 = 61 - __builtin_clzll((unsigned long long)p2[2]);
    int c3 = 61 - __builtin_clzll((unsigned long long)p2[3]);

    if (swz_out) {
        // swizzled in-place write: gcol = hf*128 + n*16 + cN ->
        // region base + hf*2048 + n*256 + (c>>2)*64 + (c&3)*16 + r
        float* Xw = X + (size_t)tl * NPTS * 256
                  + (size_t)(rb * 4 + g) * 4096 + (size_t)hf * 2048;
        int o0 = (c0 >> 2) * 64 + (c0 & 3) * 16 + r0;
        int o1 = (c1 >> 2) * 64 + (c1 & 3) * 16 + r1;
        int o2 = (c2 >> 2) * 64 + (c2 & 3) * 16 + r2;
        int o3 = (c3 >> 2) * 64 + (c3 & 3) * 16 + r3;
#define EPTS(n) {                                                              \
        int cb0 = (n) * 16;                                                    \
        float* Pn = Xw + (n) * 256;                                            \
        Pn[o0] = sin30(acc##n[0] + (double)cbp[cb0 + c0]);                     \
        Pn[o1] = sin30(acc##n[1] + (double)cbp[cb0 + c1]);                     \
        Pn[o2] = sin30(acc##n[2] + (double)cbp[cb0 + c2]);                     \
        Pn[o3] = sin30(acc##n[3] + (double)cbp[cb0 + c3]); }
        EPTS(0) EPTS(1) EPTS(2) EPTS(3)
        EPTS(4) EPTS(5) EPTS(6) EPTS(7)
#undef EPTS
    } else {
        // plain in-place write (layer 3 -> final_k)
        float* Xw = X + ((size_t)tl * NPTS + (size_t)(rb * 64 + g * 16)) * 256
                  + hf * 128;
#define EPT(n) {                                                               \
        int cb0 = (n) * 16;                                                    \
        Xw[r0 * 256 + cb0 + c0] = sin30(acc##n[0] + (double)cbp[cb0 + c0]);    \
        Xw[r1 * 256 + cb0 + c1] = sin30(acc##n[1] + (double)cbp[cb0 + c1]);    \
        Xw[r2 * 256 + cb0 + c2] = sin30(acc##n[2] + (double)cbp[cb0 + c2]);    \
        Xw[r3 * 256 + cb0 + c3] = sin30(acc##n[3] + (double)cbp[cb0 + c3]); }
        EPT(0) EPT(1) EPT(2) EPT(3)
        EPT(4) EPT(5) EPT(6) EPT(7)
#undef EPT
    }
}

// ---------------------------------------------------------------------------
// Final: out[row] = (x_row . w_last)*scale + b_last, f64 dot. One wave per row.
// Reads PLAIN-layout X (layer 3 writes plain).
// ---------------------------------------------------------------------------
__global__ __launch_bounds__(256) void final_k(
    const float* __restrict__ X, const float* __restrict__ wl,
    const float* __restrict__ bl, const float* __restrict__ NSC,
    float* __restrict__ out, int tbase)
{
    int tid = threadIdx.x; int w = tid >> 6; int lane = tid & 63;
    size_t row = (size_t)blockIdx.x * 4 + w;      // local row within T t's
    double ls = (double)NSC[1024];
    float4 wv = ((const float4*)wl)[lane];
    float4 xv = *(const float4*)(X + row * 256 + lane * 4);
    double d = 0.0;
    d = fma((double)wv.x, (double)xv.x, d);
    d = fma((double)wv.y, (double)xv.y, d);
    d = fma((double)wv.z, (double)xv.z, d);
    d = fma((double)wv.w, (double)xv.w, d);
    d *= ls;
    #pragma unroll
    for (int off = 32; off > 0; off >>= 1) d += __shfl_down(d, off, 64);
    if (lane == 0) out[(size_t)tbase * NPTS + row] = (float)(d + (double)bl[0]);
}

extern "C" void kernel_launch(void* const* d_in, const int* in_sizes, int n_in,
                              void* d_out, int out_size, void* d_ws, size_t ws_size,
                              hipStream_t stream)
{
    const float* coords     = (const float*)d_in[0];
    const float* latents    = (const float*)d_in[1];
    const float* nf_w_first = (const float*)d_in[2];
    const float* nf_b_first = (const float*)d_in[3];
    const float* nf_c_first = (const float*)d_in[4];
    const float* nf_w_hid   = (const float*)d_in[5];
    const float* nf_b_hid   = (const float*)d_in[6];
    const float* nf_c_hid   = (const float*)d_in[7];
    const float* nf_w_last  = (const float*)d_in[8];
    const float* nf_b_last  = (const float*)d_in[9];
    const float* nf_c_last  = (const float*)d_in[10];
    const float* Aw_first   = (const float*)d_in[11];
    const float* Ac_first   = (const float*)d_in[12];
    const float* Aw_hid     = (const float*)d_in[13];
    const float* Ac_hid     = (const float*)d_in[14];
    const float* Bw         = (const float*)d_in[15];
    const float* Bc         = (const float*)d_in[16];
    const float* hbw        = (const float*)d_in[17];
    const float* hbc        = (const float*)d_in[18];

    float* ws  = (float*)d_ws;
    float* Mb  = ws + OFF_M;
    float* CBb = ws + OFF_CB;
    float* AF  = ws + OFF_AF;
    float* BFb = ws + OFF_BF;
    float* HBb = ws + OFF_HB;
    float* NSC = ws + OFF_NSC;
    float* Bz  = ws + OFF_BSWZ;
    float* out = (float*)d_out;

    // single X buffer (in-place layers): pick largest T that fits
    size_t availf = ws_size / sizeof(float);
    size_t xslice = (size_t)NPTS * 256;           // floats per t-slice
    int T = 2;
    if (availf >= OFF_X0 + 8ull * xslice)      T = 8;
    else if (availf >= OFF_X0 + 4ull * xslice) T = 4;
    float* X0 = ws + OFF_X0;

    setup1<<<233, 256, 0, stream>>>(latents, Aw_first, Ac_first, Aw_hid, Ac_hid,
                                    Bw, Bc, hbw, hbc,
                                    nf_w_first, nf_c_first, nf_w_hid, nf_c_hid,
                                    nf_w_last, nf_c_last,
                                    AF, BFb, HBb, NSC);
    setup2<<<392, 256, 0, stream>>>(nf_w_first, nf_b_first, nf_w_hid, nf_b_hid,
                                    AF, BFb, HBb, NSC, Mb, CBb);
    setup3<<<8192, 256, 0, stream>>>(Mb, Bz);
    for (int tbase = 0; tbase < 8; tbase += T) {
        layer0_k<<<1024 * T, 256, 0, stream>>>(coords, Mb, CBb, X0, tbase);
        gemm_sin<<<512 * T, 512, 0, stream>>>(X0, Bz, CBb, 1, tbase, 1);
        gemm_sin<<<512 * T, 512, 0, stream>>>(X0, Bz, CBb, 2, tbase, 1);
        gemm_sin<<<512 * T, 512, 0, stream>>>(X0, Bz, CBb, 3, tbase, 0);
        final_k<<<T * 8192, 256, 0, stream>>>(X0, nf_w_last, nf_b_last, NSC, out, tbase);
    }
}